// Round 14
// baseline (186.657 us; speedup 1.0000x reference)
//
#include <hip/hip_runtime.h>
#include <hip/hip_bf16.h>

#define D_MODEL 1024
#define N_HEADS 16
#define HEAD_DIM 64
#define SEQ 2048
#define BATCH 2

typedef __attribute__((ext_vector_type(8))) short bf16x8;
typedef __attribute__((ext_vector_type(4))) short bf16x4;
typedef __attribute__((ext_vector_type(4))) float f32x4;
typedef __attribute__((ext_vector_type(16))) float f32x16;

typedef __attribute__((address_space(3))) unsigned lds_uint;
typedef __attribute__((address_space(1))) const unsigned global_cuint;

__device__ __forceinline__ void async_cp16(const ushort* g, ushort* l) {
  __builtin_amdgcn_global_load_lds((global_cuint*)g, (lds_uint*)l, 16, 0, 0);
}

__device__ __forceinline__ ushort f2b(float f) {
  union { float f; unsigned u; } x; x.f = f;
  unsigned r = x.u + 0x7fffu + ((x.u >> 16) & 1u);
  return (ushort)(r >> 16);
}

// packed f32x2 -> bf16x2; low word = a
__device__ __forceinline__ unsigned pk2(float a, float b) {
  __hip_bfloat162 h = __float22bfloat162_rn(float2{a, b});
  union { __hip_bfloat162 h; unsigned u; } x; x.h = h;
  return x.u;
}

__device__ __forceinline__ float blo(unsigned u) {
  union { unsigned u; float f; } x; x.u = u << 16; return x.f;
}
__device__ __forceinline__ float bhi(unsigned u) {
  union { unsigned u; float f; } x; x.u = u & 0xffff0000u; return x.f;
}

// sigma: swap bits 2 and 3 of a token index (involution, within 16-token
// groups). K stored at row sigma(t) makes the attn S^T C-layout's e[] order
// coincide with the 32x32x16 PV A-operand key order -> zero-shuffle K=16 PV.
__device__ __forceinline__ int sigma23(int t) {
  return (t & ~12) | ((t & 4) << 1) | ((t & 8) >> 1);
}

// XOR-swizzled ushort index into a [64][64] (128 B/row) LDS tile.
// byte_off within row ^= (row&7)<<4. With pre-swizzled global staging
// (source 16B-slot = (l&7)^(l>>3)) the staging write is lane-linear and
// all b128 frag reads distribute exactly 8 lanes per 16B slot.
__device__ __forceinline__ int swz64(int row, int colbyte) {
  return row * 64 + ((colbyte ^ ((row & 7) << 4)) >> 1);
}

// Single fused cast: x (1M uint4) + Wq/Wk/Wv (-> wqkv) + Wo (-> wob).
__global__ __launch_bounds__(256) void cast_all(const float* __restrict__ x,
                                                const float* __restrict__ Wq,
                                                const float* __restrict__ Wk,
                                                const float* __restrict__ Wv,
                                                const float* __restrict__ Wo,
                                                ushort* __restrict__ xb,
                                                ushort* __restrict__ wqkv,
                                                ushort* __restrict__ wob) {
  int idx = blockIdx.x * 256 + threadIdx.x;  // 0 .. 2M-1 (uint4 units)
  const float* in;
  uint2* out;
  if (idx < (1 << 20)) {
    in = x; out = (uint2*)xb;
  } else {
    int j = idx - (1 << 20);
    int w = j >> 18;            // 0..3
    idx = j & 0x3FFFF;          // 256K uint4 per weight
    switch (w) {
      case 0: in = Wq; out = (uint2*)wqkv; break;
      case 1: in = Wk; out = (uint2*)(wqkv) + (1 << 18); break;
      case 2: in = Wv; out = (uint2*)(wqkv) + (2 << 18); break;
      default: in = Wo; out = (uint2*)wob; break;
    }
  }
  float4 v = ((const float4*)in)[idx];
  uint2 o; o.x = pk2(v.x, v.y); o.y = pk2(v.z, v.w);
  out[idx] = o;
}

// Fused QKV projection: A = xb (4096x1024 bf16), Bw = wqkv (3072x1024 bf16).
// 128x128 tile, BK=64. R23 structure: 512-thread blocks (8 waves, 2Mx4N wave
// grid, 64x32 wave tile) -> 16 waves/CU at 64 KB dbuf. R24: K tokens stored
// at sigma23-permuted rows; Q and V^T unchanged.
// n<1024 -> Q (scaled), <2048 -> K, else -> V^T (packed b64 stores along t).
__global__ __launch_bounds__(512, 2) void gemm_qkv(const ushort* __restrict__ A,
                                                   const ushort* __restrict__ Bw,
                                                   ushort* __restrict__ Qh,
                                                   ushort* __restrict__ Kh,
                                                   ushort* __restrict__ Vth,
                                                   float qscale) {
  constexpr int K = 1024;
  const int bm = blockIdx.y * 128;
  const int bn = blockIdx.x * 128;
  const int tid = threadIdx.x;        // 0..511
  const int wave = tid >> 6;          // 0..7
  const int lane = tid & 63;
  const int l16 = lane & 15;
  const int quad = lane >> 4;

  __shared__ ushort As[2][128 * 64];   // 32 KB (dbuf)
  __shared__ ushort Bs[2][128 * 64];   // 32 KB (dbuf)

  const int wm = (wave & 1) * 64;      // 2 M-waves
  const int wn = (wave >> 1) * 32;     // 4 N-waves

  f32x4 acc[4][2];
#pragma unroll
  for (int r = 0; r < 4; ++r)
#pragma unroll
    for (int c = 0; c < 2; ++c) acc[r][c] = (f32x4){0.f, 0.f, 0.f, 0.f};

  // staging: per instruction round, 512 lanes x 16B = 64 rows x 128B.
  const int srow = wave * 8 + (lane >> 3);            // 0..63
  const int csw = (((lane & 7) ^ (lane >> 3)) << 3);  // pre-swizzled col (ushorts)

  // prologue: tile 0 -> buf 0
#pragma unroll
  for (int j = 0; j < 2; ++j) {
    async_cp16(A  + (size_t)(bm + j * 64 + srow) * K + csw, &As[0][(j * 64 + wave * 8) * 64]);
    async_cp16(Bw + (size_t)(bn + j * 64 + srow) * K + csw, &Bs[0][(j * 64 + wave * 8) * 64]);
  }

  constexpr int NIT = K / 64;  // 16
  for (int kt = 0; kt < NIT; ++kt) {
    __syncthreads();  // vmcnt(0) drain: tile kt landed; prior reads of buf^1 done
    const int buf = kt & 1;
    if (kt + 1 < NIT) {
      const int k0 = (kt + 1) * 64;
#pragma unroll
      for (int j = 0; j < 2; ++j) {
        async_cp16(A  + (size_t)(bm + j * 64 + srow) * K + k0 + csw, &As[buf ^ 1][(j * 64 + wave * 8) * 64]);
        async_cp16(Bw + (size_t)(bn + j * 64 + srow) * K + k0 + csw, &Bs[buf ^ 1][(j * 64 + wave * 8) * 64]);
      }
    }

    bf16x8 a[2][4], b[2][2];
#pragma unroll
    for (int ks = 0; ks < 2; ++ks) {
#pragma unroll
      for (int r = 0; r < 4; ++r)
        a[ks][r] = *(const bf16x8*)(&As[buf][swz64(wm + r * 16 + l16, ks * 64 + quad * 16)]);
#pragma unroll
      for (int c = 0; c < 2; ++c)
        b[ks][c] = *(const bf16x8*)(&Bs[buf][swz64(wn + c * 16 + l16, ks * 64 + quad * 16)]);
    }
#pragma unroll
    for (int ks = 0; ks < 2; ++ks)
#pragma unroll
      for (int r = 0; r < 4; ++r)
#pragma unroll
        for (int c = 0; c < 2; ++c)
          acc[r][c] = __builtin_amdgcn_mfma_f32_16x16x32_bf16(a[ks][r], b[ks][c], acc[r][c], 0, 0, 0);
  }

#pragma unroll
  for (int r = 0; r < 4; ++r) {
#pragma unroll
    for (int c = 0; c < 2; ++c) {
      int ncol = bn + wn + c * 16 + l16;   // w uniform per (block,wave,c)
      int w = ncol >> 10;
      int f = ncol & 1023;
      int h = f >> 6, d = f & 63;
      if (w == 2) {
        // V^T: 4 consecutive tokens per lane -> one b64 store (unpermuted)
        int m0 = bm + wm + r * 16 + quad * 4;
        int b = m0 >> 11, t0 = m0 & 2047;
        uint2 pp;
        pp.x = pk2(acc[r][c][0], acc[r][c][1]);
        pp.y = pk2(acc[r][c][2], acc[r][c][3]);
        *(uint2*)(&Vth[((size_t)(b * 1024 + f) << 11) + t0]) = pp;
      } else {
#pragma unroll
        for (int rr = 0; rr < 4; ++rr) {
          float v = acc[r][c][rr];
          int m = bm + wm + r * 16 + quad * 4 + rr;
          int b = m >> 11, t = m & 2047;
          if (w == 0)
            Qh[((size_t)(b * 16 + h) * SEQ + t) * 64 + d] = f2b(v * qscale);
          else
            Kh[((size_t)(b * 16 + h) * SEQ + sigma23(t)) * 64 + d] = f2b(v);
        }
      }
    }
  }
}

// Output projection: A = ctx (4096x1024 bf16), Bw = wob, fp32 out.
// 64x128 tile, BK=64. Dbuf + swizzle (R15).
__global__ __launch_bounds__(256) void gemm_out(const ushort* __restrict__ A,
                                                const ushort* __restrict__ Bw,
                                                float* __restrict__ out) {
  constexpr int K = 1024;
  const int bm = blockIdx.y * 64;
  const int bn = blockIdx.x * 128;
  const int tid = threadIdx.x;
  const int wave = tid >> 6;
  const int lane = tid & 63;
  const int l16 = lane & 15;
  const int quad = lane >> 4;

  __shared__ ushort As[2][64 * 64];    // 16 KB (dbuf)
  __shared__ ushort Bs[2][128 * 64];   // 32 KB (dbuf)

  const int wm = (wave & 1) * 32;
  const int wn = (wave >> 1) * 64;

  f32x4 acc[2][4];
#pragma unroll
  for (int r = 0; r < 2; ++r)
#pragma unroll
    for (int c = 0; c < 4; ++c) acc[r][c] = (f32x4){0.f, 0.f, 0.f, 0.f};

  const int srow = wave * 8 + (lane >> 3);
  const int csw = (((lane & 7) ^ (lane >> 3)) << 3);  // pre-swizzled col (ushorts)

  // prologue: tile 0 -> buf 0
#pragma unroll
  for (int j = 0; j < 2; ++j)
    async_cp16(A + (size_t)(bm + j * 32 + srow) * K + csw, &As[0][(j * 32 + wave * 8) * 64]);
#pragma unroll
  for (int j = 0; j < 4; ++j)
    async_cp16(Bw + (size_t)(bn + j * 32 + srow) * K + csw, &Bs[0][(j * 32 + wave * 8) * 64]);

  constexpr int NIT = K / 64;  // 16
  for (int kt = 0; kt < NIT; ++kt) {
    __syncthreads();
    const int buf = kt & 1;
    if (kt + 1 < NIT) {
      const int k0 = (kt + 1) * 64;
#pragma unroll
      for (int j = 0; j < 2; ++j)
        async_cp16(A + (size_t)(bm + j * 32 + srow) * K + k0 + csw, &As[buf ^ 1][(j * 32 + wave * 8) * 64]);
#pragma unroll
      for (int j = 0; j < 4; ++j)
        async_cp16(Bw + (size_t)(bn + j * 32 + srow) * K + k0 + csw, &Bs[buf ^ 1][(j * 32 + wave * 8) * 64]);
    }

    bf16x8 a[2][2], b[2][4];
#pragma unroll
    for (int ks = 0; ks < 2; ++ks) {
#pragma unroll
      for (int r = 0; r < 2; ++r)
        a[ks][r] = *(const bf16x8*)(&As[buf][swz64(wm + r * 16 + l16, ks * 64 + quad * 16)]);
#pragma unroll
      for (int c = 0; c < 4; ++c)
        b[ks][c] = *(const bf16x8*)(&Bs[buf][swz64(wn + c * 16 + l16, ks * 64 + quad * 16)]);
    }
#pragma unroll
    for (int ks = 0; ks < 2; ++ks)
#pragma unroll
      for (int r = 0; r < 2; ++r)
#pragma unroll
        for (int c = 0; c < 4; ++c)
          acc[r][c] = __builtin_amdgcn_mfma_f32_16x16x32_bf16(a[ks][r], b[ks][c], acc[r][c], 0, 0, 0);
  }

#pragma unroll
  for (int r = 0; r < 2; ++r)
#pragma unroll
    for (int c = 0; c < 4; ++c)
#pragma unroll
      for (int rr = 0; rr < 4; ++rr) {
        int m = bm + wm + r * 16 + quad * 4 + rr;
        int n = bn + wn + c * 16 + l16;
        out[(size_t)m * D_MODEL + n] = acc[r][c][rr];
      }
}

// Flash attention, R25: halve LDS-read traffic via 64 q-rows per wave.
// R24 counters: MfmaUtil 28 / VALUBusy 45 / attn 49us. LDS arithmetic: the
// 4 waves of a block read IDENTICAL ka/vb fragments (they depend only on
// (l31,hi)) -> 4x16 b128/block-kt = ~20us of LDS-pipe time + ~7us conflicts
// = the dominant cost. R25: 128-thread blocks (2 waves), each wave owns 64
// q-rows (2 q-groups g=0,1). ka/vb are loaded ONCE per kt2 and reused by
// both g -> total LDS reads halve. The 2 q-group chains (QK->exp2->pack->PV)
// are independent -> 2x in-wave ILP compensates the halved wave count.
// VGPR ~200 (o 64 + qf 32 + ka 32 + vb 32 + e 16 + misc); (128,2) = 256-reg
// budget, no spill risk. Same 32 KB LDS, same grid (1024 blocks), same
// sigma23 zero-shuffle K=16 PV as R24.
__global__ __launch_bounds__(128, 2) void attn_kernel(const ushort* __restrict__ Qh,
                                                      const ushort* __restrict__ Kh,
                                                      const ushort* __restrict__ Vth,
                                                      ushort* __restrict__ O1,
                                                      ushort* __restrict__ O2,
                                                      float* __restrict__ l1,
                                                      float* __restrict__ l2) {
  const int id = blockIdx.x;
  const int stream = id & 63;       // bh*2 + half
  const int qb = id >> 6;           // 0..15
  const int bh = stream >> 1;
  const int half = stream & 1;
  const int q0 = qb * 128;
  ushort* __restrict__ Op = half ? O2 : O1;
  float* __restrict__ lp = half ? l2 : l1;

  const int tid = threadIdx.x;      // 0..127
  const int wave = tid >> 6;        // 0..1
  const int lane = tid & 63;
  const int l31 = lane & 31;
  const int hi = lane >> 5;

  __shared__ ushort KVbuf[2][2][64 * 64];  // 32 KB: [buf][0=K,1=V^T], swizzled

  // Q frags (B-op of QK): col = l31 = q (within group), k = d = dc*16+hi*8+j
  bf16x8 qf[2][4];
#pragma unroll
  for (int g = 0; g < 2; ++g)
#pragma unroll
    for (int dc = 0; dc < 4; ++dc)
      qf[g][dc] = *(const bf16x8*)(Qh + ((size_t)bh * SEQ + q0 + wave * 64 + g * 32 + l31) * 64 + dc * 16 + hi * 8);

  f32x16 o[2][2];  // [g][d-half]
#pragma unroll
  for (int g = 0; g < 2; ++g)
#pragma unroll
    for (int dh = 0; dh < 2; ++dh)
      o[g][dh] = (f32x16){0.f, 0.f, 0.f, 0.f, 0.f, 0.f, 0.f, 0.f,
                          0.f, 0.f, 0.f, 0.f, 0.f, 0.f, 0.f, 0.f};
  float lacc[2] = {0.f, 0.f};

  // staging geometry: 2 waves; wave w covers chunks 4w..4w+3 (8 rows each).
  // Source 16B-slot pre-swizzled so the lane-linear LDS write lands at swz64.
  const int cb = wave * 4;
  const int r8 = lane >> 3;
  const int csw = (((lane & 7) ^ r8) << 3);   // ushort offset within 64
  const ushort* kbase = Kh + ((size_t)bh * SEQ + half * 1024) * 64;
  const ushort* vbase = Vth + (size_t)bh * 64 * SEQ + half * 1024;
  const ushort* ksrc = kbase + (size_t)(cb * 8 + r8) * 64 + csw;   // +jk*8 rows, +kt*4096
  const ushort* vsrc = vbase + (size_t)(cb * 8 + r8) * SEQ + csw;  // +jk*8 rows, +kt*64

  // prologue: tile 0 -> buf 0 (4 K + 4 V chunks per thread)
#pragma unroll
  for (int jk = 0; jk < 4; ++jk) {
    async_cp16(ksrc + (size_t)jk * 8 * 64,  &KVbuf[0][0][(cb + jk) * 512]);
    async_cp16(vsrc + (size_t)jk * 8 * SEQ, &KVbuf[0][1][(cb + jk) * 512]);
  }

  constexpr int NIT = 1024 / 64;  // 16
  for (int kt = 0; kt < NIT; ++kt) {
    __syncthreads();  // drains vmcnt: tile kt landed; prior reads of buf^1 done
    const int buf = kt & 1;
    if (kt + 1 < NIT) {
      const ushort* ks = ksrc + (size_t)(kt + 1) * 64 * 64;
      const ushort* vs = vsrc + (kt + 1) * 64;
#pragma unroll
      for (int jk = 0; jk < 4; ++jk) {
        async_cp16(ks + (size_t)jk * 8 * 64,  &KVbuf[buf ^ 1][0][(cb + jk) * 512]);
        async_cp16(vs + (size_t)jk * 8 * SEQ, &KVbuf[buf ^ 1][1][(cb + jk) * 512]);
      }
    }
    const ushort* Kt = KVbuf[buf][0];
    const ushort* Vt = KVbuf[buf][1];

#pragma unroll
    for (int kt2 = 0; kt2 < 2; ++kt2) {
      // K frags (shared by both q-groups): row = sigma-slot kt2*32+l31, k = d
      bf16x8 ka0 = *(const bf16x8*)(&Kt[swz64(kt2 * 32 + l31, 0 * 32 + hi * 16)]);
      bf16x8 ka1 = *(const bf16x8*)(&Kt[swz64(kt2 * 32 + l31, 1 * 32 + hi * 16)]);
      bf16x8 ka2 = *(const bf16x8*)(&Kt[swz64(kt2 * 32 + l31, 2 * 32 + hi * 16)]);
      bf16x8 ka3 = *(const bf16x8*)(&Kt[swz64(kt2 * 32 + l31, 3 * 32 + hi * 16)]);
      // V frags (shared by both q-groups): [lw][d-half]
      bf16x8 vb[2][2];
#pragma unroll
      for (int lw = 0; lw < 2; ++lw) {
        const int wb = (kt2 * 2 + lw) * 32;  // window byte col in V^T
        vb[lw][0] = *(const bf16x8*)(&Vt[swz64(0 + l31, wb + hi * 16)]);
        vb[lw][1] = *(const bf16x8*)(&Vt[swz64(32 + l31, wb + hi * 16)]);
      }

#pragma unroll
      for (int g = 0; g < 2; ++g) {
        f32x16 z = {0.f, 0.f, 0.f, 0.f, 0.f, 0.f, 0.f, 0.f,
                    0.f, 0.f, 0.f, 0.f, 0.f, 0.f, 0.f, 0.f};
        z = __builtin_amdgcn_mfma_f32_32x32x16_bf16(ka0, qf[g][0], z, 0, 0, 0);
        z = __builtin_amdgcn_mfma_f32_32x32x16_bf16(ka1, qf[g][1], z, 0, 0, 0);
        z = __builtin_amdgcn_mfma_f32_32x32x16_bf16(ka2, qf[g][2], z, 0, 0, 0);
        z = __builtin_amdgcn_mfma_f32_32x32x16_bf16(ka3, qf[g][3], z, 0, 0, 0);

        float e[16];
#pragma unroll
        for (int r = 0; r < 16; ++r) e[r] = __builtin_amdgcn_exp2f(z[r]);
        lacc[g] += (((e[0] + e[1]) + (e[2] + e[3])) + ((e[4] + e[5]) + (e[6] + e[7])))
                 + (((e[8] + e[9]) + (e[10] + e[11])) + ((e[12] + e[13]) + (e[14] + e[15])));

        // PV, zero-shuffle K=16 (sigma23-permuted K producer): e[8lw+j] at
        // C-row (j&3)+8(j>>2)+4hi -> key 16lw+8hi+j = A k-slot. Direct pack.
#pragma unroll
        for (int lw = 0; lw < 2; ++lw) {
          const int base = lw * 8;
          union { unsigned u[4]; bf16x8 v; } pu;
          pu.u[0] = pk2(e[base + 0], e[base + 1]);
          pu.u[1] = pk2(e[base + 2], e[base + 3]);
          pu.u[2] = pk2(e[base + 4], e[base + 5]);
          pu.u[3] = pk2(e[base + 6], e[base + 7]);
          o[g][0] = __builtin_amdgcn_mfma_f32_32x32x16_bf16(pu.v, vb[lw][0], o[g][0], 0, 0, 0);
          o[g][1] = __builtin_amdgcn_mfma_f32_32x32x16_bf16(pu.v, vb[lw][1], o[g][1], 0, 0, 0);
        }
      }
    }
  }

  // l: lane and lane+32 hold complementary key-halves of the same q.
#pragma unroll
  for (int g = 0; g < 2; ++g) {
    float ltot = lacc[g] + __shfl_xor(lacc[g], 32, 64);
    if (hi == 0)
      lp[(size_t)bh * SEQ + q0 + wave * 64 + g * 32 + l31] = ltot;
  }

  // O-store: scatter o into LDS [128][64] (q-row major), then coalesced
  // full-line uint4 copy-out. C layout: row q = (r&3)+8*(r>>2)+4*hi, col d.
  __syncthreads();  // all waves done with K/V LDS
  ushort* Ob = &KVbuf[0][0][0];  // 16 KB region
#pragma unroll
  for (int g = 0; g < 2; ++g)
#pragma unroll
    for (int r = 0; r < 16; ++r) {
      int row = wave * 64 + g * 32 + (r & 3) + 8 * (r >> 2) + 4 * hi;
      Ob[row * 64 + l31] = f2b(o[g][0][r]);
      Ob[row * 64 + 32 + l31] = f2b(o[g][1][r]);
    }
  __syncthreads();  // O tile visible
  {
    uint4* dst = (uint4*)(Op + ((size_t)bh * SEQ + q0) * 64);
    const uint4* src = (const uint4*)Ob;
#pragma unroll
    for (int i = 0; i < 8; ++i)
      dst[i * 128 + tid] = src[i * 128 + tid];
  }
}

// ctx = (O1 + O2) / (l1 + l2), routed to (B, T, D_MODEL) bf16
__global__ __launch_bounds__(256) void recombine(const ushort* __restrict__ O1,
                                                 const ushort* __restrict__ O2,
                                                 const float* __restrict__ l1,
                                                 const float* __restrict__ l2,
                                                 ushort* __restrict__ ctx) {
  int idx = blockIdx.x * 256 + threadIdx.x;   // over (BH*T*64)/8 uint4 chunks
  int row = idx >> 3;                         // bh*SEQ + t
  int d8 = idx & 7;
  uint4 a = ((const uint4*)O1)[idx];
  uint4 b = ((const uint4*)O2)[idx];
  float linv = 1.f / (l1[row] + l2[row]);
  uint4 res;
  unsigned* ap = (unsigned*)&a;
  unsigned* bp = (unsigned*)&b;
  unsigned* rp = (unsigned*)&res;
#pragma unroll
  for (int i = 0; i < 4; ++i) {
    float lo = (blo(ap[i]) + blo(bp[i])) * linv;
    float hi = (bhi(ap[i]) + bhi(bp[i])) * linv;
    rp[i] = pk2(lo, hi);
  }
  int bh = row >> 11, t = row & 2047;
  int bb = bh >> 4, h = bh & 15;
  ((uint4*)ctx)[(size_t)(bb * SEQ + t) * 128 + h * 8 + d8] = res;
}

extern "C" void kernel_launch(void* const* d_in, const int* in_sizes, int n_in,
                              void* d_out, int out_size, void* d_ws, size_t ws_size,
                              hipStream_t stream) {
  const float* x  = (const float*)d_in[0];
  const float* Wq = (const float*)d_in[1];
  const float* Wk = (const float*)d_in[2];
  const float* Wv = (const float*)d_in[3];
  const float* Wo = (const float*)d_in[4];
  float* out = (float*)d_out;

  char* ws = (char*)d_ws;
  const size_t MB = 1 << 20;
  ushort* xb   = (ushort*)(ws);             // 8 MB (dead after gemm_qkv -> O2)
  ushort* wqkv = (ushort*)(ws +  8 * MB);   // 6 MB (dead after gemm_qkv -> l1/l2)
  ushort* wob  = (ushort*)(ws + 14 * MB);   // 2 MB (live until gemm_out)
  ushort* Qh   = (ushort*)(ws + 16 * MB);   // 8 MB (BH,T,64)
  ushort* Kh   = (ushort*)(ws + 24 * MB);   // 8 MB (BH,T,64)
  ushort* Vth  = (ushort*)(ws + 32 * MB);   // 8 MB (BH,64,T)
  ushort* ctx  = (ushort*)(ws + 40 * MB);   // 8 MB (B,T,D)

  // split-K partials (regions dead during attn):
  ushort* O1 = (ushort*)d_out;              // 8 MB of the 16 MB output buffer
  ushort* O2 = xb;                          // xb region, dead after gemm_qkv
  float*  l1 = (float*)wqkv;                // 256 KB
  float*  l2 = (float*)(ws + 8 * MB + 256 * 1024);

  cast_all<<<8192, 256, 0, stream>>>(x, Wq, Wk, Wv, Wo, xb, wqkv, wob);

  const float qscale = 0.125f * 1.44269504089f;  // SCALE * log2(e)
  gemm_qkv<<<dim3(3072 / 128, 4096 / 128), 512, 0, stream>>>(xb, wqkv, Qh, Kh, Vth, qscale);

  // 1D grid, 1024 blocks of 128 threads: id = qb*64 + (bh*2+half)
  attn_kernel<<<(SEQ / 128) * BATCH * N_HEADS * 2, 128, 0, stream>>>(
      Qh, Kh, Vth, O1, O2, l1, l2);

  recombine<<<(BATCH * N_HEADS * SEQ * 64 / 8) / 256, 256, 0, stream>>>(O1, O2, l1, l2, ctx);

  gemm_out<<<dim3(1024 / 128, 4096 / 64), 256, 0, stream>>>(ctx, wob, out);
}